// Round 1
// baseline (344.038 us; speedup 1.0000x reference)
//
#include <hip/hip_runtime.h>
#include <hip/hip_bf16.h>

#define N 8192
#define Dd 128

typedef short short8 __attribute__((ext_vector_type(8)));
typedef float floatx4 __attribute__((ext_vector_type(4)));

// round-to-nearest-even fp32 -> bf16 (no NaN in inputs)
static __device__ inline unsigned short f2bf(float f) {
    unsigned int u = __float_as_uint(f);
    return (unsigned short)((u + 0x7fffu + ((u >> 16) & 1u)) >> 16);
}
static __device__ inline float bf2f(unsigned short b) {
    return __uint_as_float(((unsigned int)b) << 16);
}

// One wave per row: convert to bf16, store, and compute row norm of the
// *rounded* values so the gram diagonal cancels exactly.
__global__ __launch_bounds__(256) void prep_kernel(const float* __restrict__ z,
                                                   unsigned short* __restrict__ zb,
                                                   float* __restrict__ sq) {
    int row  = blockIdx.x * 4 + (threadIdx.x >> 6);
    int lane = threadIdx.x & 63;
    float2 v = ((const float2*)z)[row * 64 + lane];
    unsigned short b0 = f2bf(v.x);
    unsigned short b1 = f2bf(v.y);
    float f0 = bf2f(b0), f1 = bf2f(b1);
    ushort2 st; st.x = b0; st.y = b1;
    ((ushort2*)zb)[row * 64 + lane] = st;
    float s = f0 * f0 + f1 * f1;
    #pragma unroll
    for (int off = 32; off > 0; off >>= 1) s += __shfl_down(s, off, 64);
    if (lane == 0) sq[row] = s;
}

// R5: LDS-free. zb is 2 MiB total -> resident in every XCD's 4 MiB L2 (and
// panels L1-cache), so MFMA fragments load STRAIGHT from global to VGPRs:
// each wave-load touches 16 rows x 64 B contiguous segments (64 B-granular
// scatter, L2-native). This deletes both __syncthreads() (R4: the staging
// barrier serialized intra-block phases -> store-stream gaps), all LDS
// traffic, and the 32 KB LDS occupancy cap. Every wave is an independent
// load -> MFMA -> exp -> store pipeline; occupancy 16 -> ~20 waves/CU.
// Stores unchanged: direct scattered dwords, j innermost (R2 LDS-transpose
// and R3 nt-stores both regressed).
__global__ __launch_bounds__(256, 5) void pairsim_kernel(const unsigned short* __restrict__ zb,
                                                         const float* __restrict__ sq,
                                                         float* __restrict__ out) {
    int bx = blockIdx.x, by = blockIdx.y;
    int colBase = bx * 64, rowBase = by * 64;
    int t = threadIdx.x;

    int w = t >> 6, lane = t & 63;
    int wr = (w >> 1) * 32, wc = (w & 1) * 32;   // 2x2 waves -> 32x32 each
    int m = lane & 15, quad = lane >> 4;

    const short8* zc = (const short8*)zb;        // 16 B chunks, 16 per row

    // Hoist all 8 A-fragments (32 VGPRs): issued back-to-back up front so
    // L2 latency overlaps; each frag used by both j-MFMAs of its ks.
    short8 af[2][4];
    #pragma unroll
    for (int i = 0; i < 2; i++) {
        size_t rbase = (size_t)(rowBase + wr + i * 16 + m) * 16 + quad;
        #pragma unroll
        for (int ks = 0; ks < 4; ks++)
            af[i][ks] = zc[rbase + ks * 4];
    }

    floatx4 zero = {0.f, 0.f, 0.f, 0.f};
    floatx4 acc[2][2];
    #pragma unroll
    for (int i = 0; i < 2; i++)
        #pragma unroll
        for (int j = 0; j < 2; j++) acc[i][j] = zero;

    #pragma unroll
    for (int ks = 0; ks < 4; ks++) {
        short8 bfr[2];
        #pragma unroll
        for (int j = 0; j < 2; j++)
            bfr[j] = zc[(size_t)(colBase + wc + j * 16 + m) * 16 + ks * 4 + quad];
        #pragma unroll
        for (int i = 0; i < 2; i++)
            #pragma unroll
            for (int j = 0; j < 2; j++)
                acc[i][j] = __builtin_amdgcn_mfma_f32_16x16x32_bf16(af[i][ks], bfr[j], acc[i][j], 0, 0, 0);
    }

    // Epilogue: exp(-max(sq_r + sq_c - 2g, 0)) straight from C-layout
    // (col = lane&15, row = quad*4 + reg). j innermost: both halves of a
    // 128B line issue consecutively.
    #pragma unroll
    for (int i = 0; i < 2; i++) {
        #pragma unroll
        for (int r = 0; r < 4; r++) {
            int row = rowBase + wr + i * 16 + quad * 4 + r;
            float sr = sq[row];
            #pragma unroll
            for (int j = 0; j < 2; j++) {
                int col = colBase + wc + j * 16 + m;
                float sc = sq[col];
                float g = acc[i][j][r];
                float e = fminf(2.0f * g - sr - sc, 0.0f);
                out[(size_t)row * N + col] = __expf(e);
            }
        }
    }
}

extern "C" void kernel_launch(void* const* d_in, const int* in_sizes, int n_in,
                              void* d_out, int out_size, void* d_ws, size_t ws_size,
                              hipStream_t stream) {
    const float* z = (const float*)d_in[0];
    unsigned short* zb = (unsigned short*)d_ws;                       // 2 MB bf16 copy
    float* sqv = (float*)((char*)d_ws + (size_t)N * Dd * sizeof(unsigned short)); // 32 KB norms
    float* out = (float*)d_out;

    prep_kernel<<<N / 4, 256, 0, stream>>>(z, zb, sqv);
    pairsim_kernel<<<dim3(128, 128), 256, 0, stream>>>(zb, sqv, out);
}

// Round 2
// 272.787 us; speedup vs baseline: 1.2612x; 1.2612x over previous
//
#include <hip/hip_runtime.h>
#include <hip/hip_bf16.h>

#define N 8192
#define Dd 128
#define NT 16   // column tiles per block (strip-mined)

typedef short short8 __attribute__((ext_vector_type(8)));
typedef float floatx4 __attribute__((ext_vector_type(4)));

// round-to-nearest-even fp32 -> bf16 (no NaN in inputs)
static __device__ inline unsigned short f2bf(float f) {
    unsigned int u = __float_as_uint(f);
    return (unsigned short)((u + 0x7fffu + ((u >> 16) & 1u)) >> 16);
}
static __device__ inline float bf2f(unsigned short b) {
    return __uint_as_float(((unsigned int)b) << 16);
}

// One wave per row: convert to bf16, store, and compute row norm of the
// *rounded* values so the gram diagonal cancels exactly.
__global__ __launch_bounds__(256) void prep_kernel(const float* __restrict__ z,
                                                   unsigned short* __restrict__ zb,
                                                   float* __restrict__ sq) {
    int row  = blockIdx.x * 4 + (threadIdx.x >> 6);
    int lane = threadIdx.x & 63;
    float2 v = ((const float2*)z)[row * 64 + lane];
    unsigned short b0 = f2bf(v.x);
    unsigned short b1 = f2bf(v.y);
    float f0 = bf2f(b0), f1 = bf2f(b1);
    ushort2 st; st.x = b0; st.y = b1;
    ((ushort2*)zb)[row * 64 + lane] = st;
    float s = f0 * f0 + f1 * f1;
    #pragma unroll
    for (int off = 32; off > 0; off >>= 1) s += __shfl_down(s, off, 64);
    if (lane == 0) sq[row] = s;
}

// R6: strip-mined double-buffered pipeline. R4's one-tile blocks serialized
// stage->barrier->MFMA->store per block (~3500cy vs 1600cy of store issue),
// and the 4 phase-aligned resident blocks left the store pipe at ~45% duty.
// Here each block owns a 64-row strip x 16 tiles: A panel staged ONCE and
// held in registers; B double-buffered via global_load_lds (linear LDS dest,
// XOR-swizzle applied by permuting the per-lane GLOBAL source address), one
// __syncthreads per iter. The barrier's vmcnt(0)/lgkmcnt(0) drain IS the
// correctness guarantee: S(k) completes before R(k), R(k-1) completes before
// S(k+1) overwrites. Staging of k+1 + store-acks of k hide under a full
// iteration of compute+store. (R5 lesson: scatter loads are fine once per
// block -- the A-frag path here is LDS, coalesced -- fatal once per tile.)
__global__ __launch_bounds__(256, 4) void pairsim_kernel(const unsigned short* __restrict__ zb,
                                                         const float* __restrict__ sq,
                                                         float* __restrict__ out) {
    __shared__ unsigned short bufA[64 * 128];   // A panel, then B write buffer
    __shared__ unsigned short bufB[64 * 128];   // B double-buffer partner

    int t = threadIdx.x;
    int w = t >> 6, lane = t & 63;
    int rowBase   = blockIdx.y * 64;
    int chunkBase = blockIdx.x * (NT * 64);

    int wr = (w >> 1) * 32, wc = (w & 1) * 32;  // 2x2 waves -> 32x32 each
    int m = lane & 15, quad = lane >> 4;

    // Staging geometry: wave w stages panel rows 16w..16w+15, 4 instrs (q).
    // Linear LDS dest (lane l -> row 16w+4q+(l>>4), slot l&15); global source
    // chunk pre-swizzled so slot s of row r holds chunk s^(r&15).
    int srow_[4], schk_[4];
    #pragma unroll
    for (int q = 0; q < 4; q++) {
        srow_[q] = 16 * w + 4 * q + (lane >> 4);
        schk_[q] = (lane & 15) ^ (4 * q + (lane >> 4));
    }
    const char* zbB = (const char*)zb;

#define STAGE(panel, growbase)                                                      \
    {                                                                               \
        _Pragma("unroll")                                                           \
        for (int q = 0; q < 4; q++) {                                               \
            const void* gsrc = zbB + (((size_t)((growbase) + srow_[q])) << 8)       \
                                   + ((size_t)schk_[q] << 4);                       \
            __builtin_amdgcn_global_load_lds(                                       \
                (const __attribute__((address_space(1))) void*)gsrc,                \
                (__attribute__((address_space(3))) void*)((char*)(panel) +          \
                                                          (16 * w + 4 * q) * 256),  \
                16, 0, 0);                                                          \
        }                                                                           \
    }

    // ---- prologue: A panel -> bufA, B tile 0 -> bufB ----
    STAGE(bufA, rowBase);
    STAGE(bufB, chunkBase);
    __syncthreads();   // vmcnt(0) drain: both panels resident

    // A fragments -> registers for the whole strip (chunk c lives at slot c^m)
    short8 af[2][4];
    #pragma unroll
    for (int i = 0; i < 2; i++)
        #pragma unroll
        for (int ks = 0; ks < 4; ks++) {
            int c = ks * 4 + quad;
            af[i][ks] = *(const short8*)&bufA[(wr + i * 16 + m) * 128 + ((c ^ m) * 8)];
        }

    float sr_[2][4];
    #pragma unroll
    for (int i = 0; i < 2; i++)
        #pragma unroll
        for (int r = 0; r < 4; r++)
            sr_[i][r] = sq[rowBase + wr + i * 16 + quad * 4 + r];

    // Per iteration: BAR -> ds_read B[k] -> issue stage B[k+1] -> MFMA ->
    // exp+store. ds_reads precede the stage so all staging is quiesced at
    // each barrier (no compiler alias-vmcnt mid-iteration).
#define ITER(k, RBUF, WBUF, DO_STAGE)                                               \
    {                                                                               \
        __syncthreads();                                                            \
        short8 bfv[2][4];                                                           \
        _Pragma("unroll")                                                           \
        for (int ks = 0; ks < 4; ks++) {                                            \
            int c = ks * 4 + quad;                                                  \
            bfv[0][ks] = *(const short8*)&(RBUF)[(wc + m) * 128 + ((c ^ m) * 8)];   \
            bfv[1][ks] = *(const short8*)&(RBUF)[(wc + 16 + m) * 128 + ((c ^ m) * 8)]; \
        }                                                                           \
        if (DO_STAGE) STAGE(WBUF, chunkBase + ((k) + 1) * 64);                      \
        floatx4 zero = {0.f, 0.f, 0.f, 0.f};                                        \
        floatx4 acc[2][2];                                                          \
        acc[0][0] = zero; acc[0][1] = zero; acc[1][0] = zero; acc[1][1] = zero;     \
        _Pragma("unroll")                                                           \
        for (int ks = 0; ks < 4; ks++) {                                            \
            _Pragma("unroll")                                                       \
            for (int i = 0; i < 2; i++)                                             \
                _Pragma("unroll")                                                   \
                for (int j = 0; j < 2; j++)                                         \
                    acc[i][j] = __builtin_amdgcn_mfma_f32_16x16x32_bf16(            \
                        af[i][ks], bfv[j][ks], acc[i][j], 0, 0, 0);                 \
        }                                                                           \
        int c0 = chunkBase + (k) * 64;                                              \
        float sc0 = sq[c0 + wc + m];                                                \
        float sc1 = sq[c0 + wc + 16 + m];                                           \
        _Pragma("unroll")                                                           \
        for (int i = 0; i < 2; i++) {                                               \
            _Pragma("unroll")                                                       \
            for (int r = 0; r < 4; r++) {                                           \
                int row = rowBase + wr + i * 16 + quad * 4 + r;                     \
                float sr = sr_[i][r];                                               \
                float g0 = acc[i][0][r];                                            \
                float g1 = acc[i][1][r];                                            \
                float e0 = fminf(2.0f * g0 - sr - sc0, 0.0f);                       \
                float e1 = fminf(2.0f * g1 - sr - sc1, 0.0f);                       \
                size_t ro = (size_t)row * N;                                        \
                out[ro + (c0 + wc + m)]      = __expf(e0);                          \
                out[ro + (c0 + wc + 16 + m)] = __expf(e1);                          \
            }                                                                       \
        }                                                                           \
    }

    #pragma unroll 1
    for (int kk = 0; kk < NT; kk += 2) {
        ITER(kk,     bufB, bufA, 1);
        ITER(kk + 1, bufA, bufB, (kk < NT - 2));
    }
#undef ITER
#undef STAGE
}

extern "C" void kernel_launch(void* const* d_in, const int* in_sizes, int n_in,
                              void* d_out, int out_size, void* d_ws, size_t ws_size,
                              hipStream_t stream) {
    const float* z = (const float*)d_in[0];
    unsigned short* zb = (unsigned short*)d_ws;                       // 2 MB bf16 copy
    float* sqv = (float*)((char*)d_ws + (size_t)N * Dd * sizeof(unsigned short)); // 32 KB norms
    float* out = (float*)d_out;

    prep_kernel<<<N / 4, 256, 0, stream>>>(z, zb, sqv);
    pairsim_kernel<<<dim3(8, 128), 256, 0, stream>>>(zb, sqv, out);
}